// Round 14
// baseline (91.884 us; speedup 1.0000x reference)
//
#include <hip/hip_runtime.h>

#define BB 4
#define NN 512
#define HH 64
#define NODES (BB*NN)
#define NSL 8            // j-slices == waves per fused block
#define JCH (NN/NSL)     // 64 j's per slice
#define TI 4             // i-nodes per block
#define REPS 9           // DIAGNOSTIC: rep the POST region (slice-sum + out
                         // stages + barriers); marginal = true post-region time.

typedef float v4f __attribute__((ext_vector_type(4)));

// ---------------- Kernel A: encoder MLP + message projections (proven R6) ----------------
__global__ __launch_bounds__(256) void enc_kernel(
    const float* __restrict__ pos,
    const float* __restrict__ enc_w1, const float* __restrict__ enc_b1,
    const float* __restrict__ enc_w2, const float* __restrict__ enc_b2,
    const float* __restrict__ msg_w1,
    float* __restrict__ h_out, float* __restrict__ ai_out, float* __restrict__ aj_out)
{
    const int w = threadIdx.x >> 6;
    const int k = threadIdx.x & 63;
    const int node = blockIdx.x*4 + w;
    __shared__ float t_s[4][HH];
    __shared__ float h_s[4][HH];

    const float px = pos[node*2+0];
    const float py = pos[node*2+1];

    float t = fmaf(px, enc_w1[k], fmaf(py, enc_w1[HH + k], enc_b1[k]));
    t_s[w][k] = fmaxf(t, 0.f);
    __syncthreads();

    float h = enc_b2[k];
    #pragma unroll
    for (int m = 0; m < HH; ++m) h = fmaf(t_s[w][m], enc_w2[m*HH + k], h);
    h_s[w][k] = h;
    h_out[node*HH + k] = h;
    __syncthreads();

    float aiv = 0.f, ajv = 0.f;
    #pragma unroll
    for (int m = 0; m < HH; ++m) {
        const float hm = h_s[w][m];
        aiv = fmaf(hm, msg_w1[m*HH + k],        aiv);
        ajv = fmaf(hm, msg_w1[(HH + m)*HH + k], ajv);
    }
    ai_out[node*HH + k] = aiv;
    aj_out[node*HH + k] = ajv;
}

// ---------------- Kernel B: R10 pairout, POST region repeated REPS times ----------------
__global__ __launch_bounds__(512, 2) void pairout_kernel(
    const float* __restrict__ pos, const int* __restrict__ box_ptr,
    const float* __restrict__ msg_w1, const float* __restrict__ msg_b1,
    const float* __restrict__ ai, const float* __restrict__ aj,
    const float* __restrict__ h_in,
    const float* __restrict__ msg_w2, const float* __restrict__ msg_b2,
    const float* __restrict__ upd_w1, const float* __restrict__ upd_b1,
    const float* __restrict__ upd_w2, const float* __restrict__ upd_b2,
    const float* __restrict__ dec_w1, const float* __restrict__ dec_b1,
    const float* __restrict__ dec_w2, const float* __restrict__ dec_b2,
    float* __restrict__ out)
{
    const int w  = threadIdx.x >> 6;     // wave id == j-slice
    const int l  = threadIdx.x & 63;
    const int jgrp = l >> 4;
    const int kq   = l & 15;
    const int ig = blockIdx.x;           // 0..511
    const int b  = ig >> 7;
    const int i0 = (ig & 127) * TI;
    const int node0 = b*NN + i0;
    const int jch0  = w * JCH;

    __shared__ float dbuf[NSL][TI*64];
    __shared__ float acc_lds[NSL][TI][HH];
    __shared__ float A [TI][HH];
    __shared__ float Hs[TI][HH];
    __shared__ float G [TI][HH];
    __shared__ float P [TI][HH];
    __shared__ float U [TI][HH];
    __shared__ float D [TI][HH];

    // ================= pair phase (all 8 waves, once — R10 verbatim) =================
    {
        const float box  = (float)box_ptr[0];
        const float hbox = 0.5f * box;
        const float2* pos2 = (const float2*)pos;
        float* db = dbuf[w];

        // prefetch all 16 aj row-loads (R10)
        v4f ajr[16];
        {
            const float* ajbase = aj + (size_t)(b*NN + jch0 + jgrp)*HH + 4*kq;
            #pragma unroll
            for (int t = 0; t < 16; ++t)
                ajr[t] = *(const v4f*)(ajbase + (size_t)t*4*HH);
        }

        const v4f wd4 = *(const v4f*)(msg_w1 + 2*HH*HH + 4*kq);
        const v4f b1  = *(const v4f*)(msg_b1 + 4*kq);
        v4f base4[TI];
        float2 pi[TI];
        #pragma unroll
        for (int ii = 0; ii < TI; ++ii) {
            base4[ii] = *(const v4f*)(ai + (size_t)(node0 + ii)*HH + 4*kq) + b1;
            pi[ii] = pos2[node0 + ii];
        }

        {
            const float2 pj = pos2[b*NN + jch0 + l];
            #pragma unroll
            for (int ii = 0; ii < TI; ++ii) {
                float dx = pj.x - pi[ii].x;
                float dy = pj.y - pi[ii].y;
                dx -= (dx >  hbox) ? box : 0.f;
                dx += (dx < -hbox) ? box : 0.f;
                dy -= (dy >  hbox) ? box : 0.f;
                dy += (dy < -hbox) ? box : 0.f;
                db[ii*64 + (l&3)*16 + (l>>2)] = sqrtf(fmaf(dx, dx, dy*dy));
            }
        }
        __builtin_amdgcn_wave_barrier();

        v4f acc[TI];
        #pragma unroll
        for (int ii = 0; ii < TI; ++ii) acc[ii] = (v4f){0.f,0.f,0.f,0.f};

        #pragma unroll
        for (int t4 = 0; t4 < 4; ++t4) {
            v4f d4[TI];
            #pragma unroll
            for (int ii = 0; ii < TI; ++ii)
                d4[ii] = *(const v4f*)(db + ii*64 + jgrp*16 + 4*t4);
            #pragma unroll
            for (int u = 0; u < 4; ++u) {
                const v4f a4 = ajr[t4*4 + u];
                #pragma unroll
                for (int ii = 0; ii < TI; ++ii) {
                    const float d = d4[ii][u];
                    v4f t = __builtin_elementwise_fma((v4f)(d), wd4, a4 + base4[ii]);
                    acc[ii] += __builtin_elementwise_max(t, (v4f){0.f,0.f,0.f,0.f});
                }
            }
        }

        #pragma unroll
        for (int ii = 0; ii < TI; ++ii) {
            #pragma unroll
            for (int c = 0; c < 4; ++c) {
                float v = acc[ii][c];
                v += __shfl_xor(v, 16, 64);
                v += __shfl_xor(v, 32, 64);
                acc[ii][c] = v;
            }
        }

        {
            const int ii = jgrp;
            const int i  = i0 + ii;
            v4f a = acc[ii];
            if ((i >> 6) == w) {
                const v4f ajs = *(const v4f*)(aj + (size_t)(b*NN + i)*HH + 4*kq);
                a -= __builtin_elementwise_max(base4[ii] + ajs, (v4f){0.f,0.f,0.f,0.f});
            }
            *(v4f*)(&acc_lds[w][ii][4*kq]) = a;
        }
    }
    __syncthreads();

    // ================= POST region, repeated REPS times =================
    const int nn  = w & 3;
    const int o   = w >> 2;
    const int jg8 = l >> 3;
    const int kq8 = l & 7;
    const int ocol = o*32 + 4*kq8;
    const float inv = 1.f / (float)(NN - 1);

    int z = 0;                           // asm-opaque zero defeats LICM
    #pragma unroll 1
    for (int rep = 0; rep < REPS; ++rep) {
        asm volatile("" : "+v"(z));
        const float* accp  = (const float*)&acc_lds[0][0][0] + z;
        const float* hinz  = h_in   + z;
        const float* mw2z  = msg_w2 + z;
        const float* mb2z  = msg_b2 + z;
        const float* uw1z  = upd_w1 + z;
        const float* ub1z  = upd_b1 + z;
        const float* uw2z  = upd_w2 + z;
        const float* ub2z  = upd_b2 + z;
        const float* dw1z  = dec_w1 + z;
        const float* db1z  = dec_b1 + z;

        // ---- slice-sum + h load ----
        if (w < 4) {
            float a = 0.f;
            #pragma unroll
            for (int s = 0; s < NSL; ++s) a += accp[(s*TI + w)*HH + l];
            A[w][l] = a;
        } else {
            const int n2 = w - 4;
            Hs[n2][l] = hinz[(size_t)(node0 + n2)*HH + l];
        }
        __syncthreads();

        // ---- stage 1: G = A @ msg_w2 * inv + msg_b2 ----
        {
            v4f q = {0.f,0.f,0.f,0.f};
            #pragma unroll
            for (int mm = 0; mm < 8; ++mm) {
                const int m = 8*mm + jg8;
                const v4f wrow = *(const v4f*)(mw2z + m*HH + ocol);
                q = __builtin_elementwise_fma((v4f)(A[nn][m]), wrow, q);
            }
            #pragma unroll
            for (int c = 0; c < 4; ++c) {
                float x = q[c];
                x += __shfl_xor(x, 8, 64);
                x += __shfl_xor(x, 16, 64);
                x += __shfl_xor(x, 32, 64);
                q[c] = x;
            }
            q = __builtin_elementwise_fma(q, (v4f)(inv), *(const v4f*)(mb2z + ocol));
            if (jg8 == 0) *(v4f*)(&G[nn][ocol]) = q;
        }
        __syncthreads();

        // ---- stage 2: P = relu(Hs @ upd_w1[:64] + G @ upd_w1[64:] + upd_b1) ----
        {
            v4f q = {0.f,0.f,0.f,0.f};
            #pragma unroll
            for (int mm = 0; mm < 8; ++mm) {
                const int m = 8*mm + jg8;
                const v4f wrow = *(const v4f*)(uw1z + m*HH + ocol);
                q = __builtin_elementwise_fma((v4f)(Hs[nn][m]), wrow, q);
            }
            #pragma unroll
            for (int mm = 0; mm < 8; ++mm) {
                const int m = 8*mm + jg8;
                const v4f wrow = *(const v4f*)(uw1z + (size_t)(HH + m)*HH + ocol);
                q = __builtin_elementwise_fma((v4f)(G[nn][m]), wrow, q);
            }
            #pragma unroll
            for (int c = 0; c < 4; ++c) {
                float x = q[c];
                x += __shfl_xor(x, 8, 64);
                x += __shfl_xor(x, 16, 64);
                x += __shfl_xor(x, 32, 64);
                q[c] = x;
            }
            q = __builtin_elementwise_max(q + *(const v4f*)(ub1z + ocol),
                                          (v4f){0.f,0.f,0.f,0.f});
            if (jg8 == 0) *(v4f*)(&P[nn][ocol]) = q;
        }
        __syncthreads();

        // ---- stage 3: U = P @ upd_w2 + upd_b2 ----
        {
            v4f q = {0.f,0.f,0.f,0.f};
            #pragma unroll
            for (int mm = 0; mm < 8; ++mm) {
                const int m = 8*mm + jg8;
                const v4f wrow = *(const v4f*)(uw2z + m*HH + ocol);
                q = __builtin_elementwise_fma((v4f)(P[nn][m]), wrow, q);
            }
            #pragma unroll
            for (int c = 0; c < 4; ++c) {
                float x = q[c];
                x += __shfl_xor(x, 8, 64);
                x += __shfl_xor(x, 16, 64);
                x += __shfl_xor(x, 32, 64);
                q[c] = x;
            }
            q = q + *(const v4f*)(ub2z + ocol);
            if (jg8 == 0) *(v4f*)(&U[nn][ocol]) = q;
        }
        __syncthreads();

        // ---- stage 4: D = relu(U @ dec_w1 + dec_b1) ----
        {
            v4f q = {0.f,0.f,0.f,0.f};
            #pragma unroll
            for (int mm = 0; mm < 8; ++mm) {
                const int m = 8*mm + jg8;
                const v4f wrow = *(const v4f*)(dw1z + m*HH + ocol);
                q = __builtin_elementwise_fma((v4f)(U[nn][m]), wrow, q);
            }
            #pragma unroll
            for (int c = 0; c < 4; ++c) {
                float x = q[c];
                x += __shfl_xor(x, 8, 64);
                x += __shfl_xor(x, 16, 64);
                x += __shfl_xor(x, 32, 64);
                q[c] = x;
            }
            q = __builtin_elementwise_max(q + *(const v4f*)(db1z + ocol),
                                          (v4f){0.f,0.f,0.f,0.f});
            if (jg8 == 0) *(v4f*)(&D[nn][ocol]) = q;
        }
        __syncthreads();
    }

    // ---- final: forces = D @ dec_w2 + dec_b2 (once; waves 0-3) ----
    if (w < 4) {
        const float d = D[w][l];
        float f0 = d * dec_w2[2*l + 0];
        float f1 = d * dec_w2[2*l + 1];
        #pragma unroll
        for (int off = 32; off >= 1; off >>= 1) {
            f0 += __shfl_xor(f0, off, 64);
            f1 += __shfl_xor(f1, off, 64);
        }
        if (l == 0) {
            out[(size_t)(node0 + w)*2 + 0] = f0 + dec_b2[0];
            out[(size_t)(node0 + w)*2 + 1] = f1 + dec_b2[1];
        }
    }
}

extern "C" void kernel_launch(void* const* d_in, const int* in_sizes, int n_in,
                              void* d_out, int out_size, void* d_ws, size_t ws_size,
                              hipStream_t stream) {
    const float* pos    = (const float*)d_in[0];
    const int*   boxp   = (const int*)  d_in[1];
    const float* enc_w1 = (const float*)d_in[2];
    const float* enc_b1 = (const float*)d_in[3];
    const float* enc_w2 = (const float*)d_in[4];
    const float* enc_b2 = (const float*)d_in[5];
    const float* msg_w1 = (const float*)d_in[6];
    const float* msg_b1 = (const float*)d_in[7];
    const float* msg_w2 = (const float*)d_in[8];
    const float* msg_b2 = (const float*)d_in[9];
    const float* upd_w1 = (const float*)d_in[10];
    const float* upd_b1 = (const float*)d_in[11];
    const float* upd_w2 = (const float*)d_in[12];
    const float* upd_b2 = (const float*)d_in[13];
    const float* dec_w1 = (const float*)d_in[14];
    const float* dec_b1 = (const float*)d_in[15];
    const float* dec_w2 = (const float*)d_in[16];
    const float* dec_b2 = (const float*)d_in[17];

    float* ws = (float*)d_ws;
    float* h  = ws;
    float* ai = ws + (size_t)NODES*HH;
    float* aj = ws + (size_t)2*NODES*HH;

    enc_kernel<<<NODES/4, 256, 0, stream>>>(pos, enc_w1, enc_b1, enc_w2, enc_b2,
                                            msg_w1, h, ai, aj);
    pairout_kernel<<<NODES/TI, 512, 0, stream>>>(pos, boxp, msg_w1, msg_b1,
                                                 ai, aj, h,
                                                 msg_w2, msg_b2,
                                                 upd_w1, upd_b1, upd_w2, upd_b2,
                                                 dec_w1, dec_b1, dec_w2, dec_b2,
                                                 (float*)d_out);
}

// Round 15
// 27.095 us; speedup vs baseline: 3.3912x; 3.3912x over previous
//
#include <hip/hip_runtime.h>

#define BB 4
#define NN 512
#define HH 64
#define NODES (BB*NN)
#define NSL 8            // j-slices == waves per fused block
#define JCH (NN/NSL)     // 64 j's per slice
#define TI 4             // i-nodes per block

typedef float v4f __attribute__((ext_vector_type(4)));

// ---------------- Kernel A: encoder MLP + message projections (proven R6) ----------------
__global__ __launch_bounds__(256) void enc_kernel(
    const float* __restrict__ pos,
    const float* __restrict__ enc_w1, const float* __restrict__ enc_b1,
    const float* __restrict__ enc_w2, const float* __restrict__ enc_b2,
    const float* __restrict__ msg_w1,
    float* __restrict__ h_out, float* __restrict__ ai_out, float* __restrict__ aj_out)
{
    const int w = threadIdx.x >> 6;
    const int k = threadIdx.x & 63;
    const int node = blockIdx.x*4 + w;
    __shared__ float t_s[4][HH];
    __shared__ float h_s[4][HH];

    const float px = pos[node*2+0];
    const float py = pos[node*2+1];

    float t = fmaf(px, enc_w1[k], fmaf(py, enc_w1[HH + k], enc_b1[k]));
    t_s[w][k] = fmaxf(t, 0.f);
    __syncthreads();

    float h = enc_b2[k];
    #pragma unroll
    for (int m = 0; m < HH; ++m) h = fmaf(t_s[w][m], enc_w2[m*HH + k], h);
    h_s[w][k] = h;
    h_out[node*HH + k] = h;
    __syncthreads();

    float aiv = 0.f, ajv = 0.f;
    #pragma unroll
    for (int m = 0; m < HH; ++m) {
        const float hm = h_s[w][m];
        aiv = fmaf(hm, msg_w1[m*HH + k],        aiv);
        ajv = fmaf(hm, msg_w1[(HH + m)*HH + k], ajv);
    }
    ai_out[node*HH + k] = aiv;
    aj_out[node*HH + k] = ajv;
}

// ---------------- Kernel B: fused pair + WAVE-LOCAL output MLP ----------------
// Pair phase: R10 verbatim (8 waves, j-slice each, ajr prefetch) -> acc_lds.
// ONE __syncthreads. Out phase: wave w<4 owns node w ENTIRELY: lane =
// (jg4 = l>>4 m-subset, kq = l&15 col-quad). Each stage is wave-local (weight
// rows 1KB/instr coalesced, LDS broadcasts, 2-shfl reduce) separated only by
// wave_barrier fences - ZERO block barriers after the pair phase (R14 probe:
// the 5-barrier stage convoy was 8.3us at 23% VALU). Waves 4-7 exit.
__global__ __launch_bounds__(512, 2) void pairout_kernel(
    const float* __restrict__ pos, const int* __restrict__ box_ptr,
    const float* __restrict__ msg_w1, const float* __restrict__ msg_b1,
    const float* __restrict__ ai, const float* __restrict__ aj,
    const float* __restrict__ h_in,
    const float* __restrict__ msg_w2, const float* __restrict__ msg_b2,
    const float* __restrict__ upd_w1, const float* __restrict__ upd_b1,
    const float* __restrict__ upd_w2, const float* __restrict__ upd_b2,
    const float* __restrict__ dec_w1, const float* __restrict__ dec_b1,
    const float* __restrict__ dec_w2, const float* __restrict__ dec_b2,
    float* __restrict__ out)
{
    const int w  = threadIdx.x >> 6;     // wave id == j-slice
    const int l  = threadIdx.x & 63;
    const int jgrp = l >> 4;
    const int kq   = l & 15;
    const int ig = blockIdx.x;           // 0..511
    const int b  = ig >> 7;
    const int i0 = (ig & 127) * TI;
    const int node0 = b*NN + i0;
    const int jch0  = w * JCH;

    __shared__ float dbuf[NSL][TI*64];
    __shared__ float acc_lds[NSL][TI][HH];
    __shared__ float A [TI][HH];
    __shared__ float Hs[TI][HH];
    __shared__ float G [TI][HH];
    __shared__ float P [TI][HH];
    __shared__ float U [TI][HH];
    __shared__ float D [TI][HH];

    // ================= pair phase (all 8 waves) — R10 verbatim =================
    {
        const float box  = (float)box_ptr[0];
        const float hbox = 0.5f * box;
        const float2* pos2 = (const float2*)pos;
        float* db = dbuf[w];

        // prefetch all 16 aj row-loads (R10, +1.1us measured)
        v4f ajr[16];
        {
            const float* ajbase = aj + (size_t)(b*NN + jch0 + jgrp)*HH + 4*kq;
            #pragma unroll
            for (int t = 0; t < 16; ++t)
                ajr[t] = *(const v4f*)(ajbase + (size_t)t*4*HH);
        }

        const v4f wd4 = *(const v4f*)(msg_w1 + 2*HH*HH + 4*kq);
        const v4f b1  = *(const v4f*)(msg_b1 + 4*kq);
        v4f base4[TI];
        float2 pi[TI];
        #pragma unroll
        for (int ii = 0; ii < TI; ++ii) {
            base4[ii] = *(const v4f*)(ai + (size_t)(node0 + ii)*HH + 4*kq) + b1;
            pi[ii] = pos2[node0 + ii];
        }

        // distances: lane l handles j = jch0 + l for all TI i's
        {
            const float2 pj = pos2[b*NN + jch0 + l];
            #pragma unroll
            for (int ii = 0; ii < TI; ++ii) {
                float dx = pj.x - pi[ii].x;
                float dy = pj.y - pi[ii].y;
                dx -= (dx >  hbox) ? box : 0.f;
                dx += (dx < -hbox) ? box : 0.f;
                dy -= (dy >  hbox) ? box : 0.f;
                dy += (dy < -hbox) ? box : 0.f;
                db[ii*64 + (l&3)*16 + (l>>2)] = sqrtf(fmaf(dx, dx, dy*dy));
            }
        }
        __builtin_amdgcn_wave_barrier();

        v4f acc[TI];
        #pragma unroll
        for (int ii = 0; ii < TI; ++ii) acc[ii] = (v4f){0.f,0.f,0.f,0.f};

        #pragma unroll
        for (int t4 = 0; t4 < 4; ++t4) {
            v4f d4[TI];
            #pragma unroll
            for (int ii = 0; ii < TI; ++ii)
                d4[ii] = *(const v4f*)(db + ii*64 + jgrp*16 + 4*t4);
            #pragma unroll
            for (int u = 0; u < 4; ++u) {
                const v4f a4 = ajr[t4*4 + u];
                #pragma unroll
                for (int ii = 0; ii < TI; ++ii) {
                    const float d = d4[ii][u];
                    v4f t = __builtin_elementwise_fma((v4f)(d), wd4, a4 + base4[ii]);
                    acc[ii] += __builtin_elementwise_max(t, (v4f){0.f,0.f,0.f,0.f});
                }
            }
        }

        #pragma unroll
        for (int ii = 0; ii < TI; ++ii) {
            #pragma unroll
            for (int c = 0; c < 4; ++c) {
                float v = acc[ii][c];
                v += __shfl_xor(v, 16, 64);
                v += __shfl_xor(v, 32, 64);
                acc[ii][c] = v;
            }
        }

        // self-term (exact: d_ii==0 -> in-loop term == relu(base+aj_i))
        {
            const int ii = jgrp;
            const int i  = i0 + ii;
            v4f a = acc[ii];
            if ((i >> 6) == w) {
                const v4f ajs = *(const v4f*)(aj + (size_t)(b*NN + i)*HH + 4*kq);
                a -= __builtin_elementwise_max(base4[ii] + ajs, (v4f){0.f,0.f,0.f,0.f});
            }
            *(v4f*)(&acc_lds[w][ii][4*kq]) = a;
        }
    }
    __syncthreads();               // the ONLY block barrier after launch

    // ================= out phase: wave w < 4 owns node w entirely =================
    if (w < 4) {
        const int nn  = w;
        const int jg4 = l >> 4;            // m-subset {4mm + jg4}
        const int col = 4*(l & 15);        // output col quad (full 64 cols)
        const float inv = 1.f / (float)(NN - 1);

        // slice-sum + h load (wave-local; lane l owns dim l)
        {
            float a = 0.f;
            #pragma unroll
            for (int s = 0; s < NSL; ++s) a += acc_lds[s][nn][l];
            A[nn][l]  = a;
            Hs[nn][l] = h_in[(size_t)(node0 + nn)*HH + l];
        }
        __builtin_amdgcn_wave_barrier();

        // ---- stage 1: G = A @ msg_w2 * inv + msg_b2 ----
        {
            v4f q = {0.f,0.f,0.f,0.f};
            #pragma unroll
            for (int mm = 0; mm < 16; ++mm) {
                const int m = 4*mm + jg4;
                const v4f wrow = *(const v4f*)(msg_w2 + m*HH + col);
                q = __builtin_elementwise_fma((v4f)(A[nn][m]), wrow, q);
            }
            #pragma unroll
            for (int c = 0; c < 4; ++c) {
                float x = q[c];
                x += __shfl_xor(x, 16, 64);
                x += __shfl_xor(x, 32, 64);
                q[c] = x;
            }
            q = __builtin_elementwise_fma(q, (v4f)(inv), *(const v4f*)(msg_b2 + col));
            if (jg4 == 0) *(v4f*)(&G[nn][col]) = q;
        }
        __builtin_amdgcn_wave_barrier();

        // ---- stage 2: P = relu(Hs @ upd_w1[:64] + G @ upd_w1[64:] + upd_b1) ----
        {
            v4f q = {0.f,0.f,0.f,0.f};
            #pragma unroll
            for (int mm = 0; mm < 16; ++mm) {
                const int m = 4*mm + jg4;
                const v4f wrow = *(const v4f*)(upd_w1 + m*HH + col);
                q = __builtin_elementwise_fma((v4f)(Hs[nn][m]), wrow, q);
            }
            #pragma unroll
            for (int mm = 0; mm < 16; ++mm) {
                const int m = 4*mm + jg4;
                const v4f wrow = *(const v4f*)(upd_w1 + (size_t)(HH + m)*HH + col);
                q = __builtin_elementwise_fma((v4f)(G[nn][m]), wrow, q);
            }
            #pragma unroll
            for (int c = 0; c < 4; ++c) {
                float x = q[c];
                x += __shfl_xor(x, 16, 64);
                x += __shfl_xor(x, 32, 64);
                q[c] = x;
            }
            q = __builtin_elementwise_max(q + *(const v4f*)(upd_b1 + col),
                                          (v4f){0.f,0.f,0.f,0.f});
            if (jg4 == 0) *(v4f*)(&P[nn][col]) = q;
        }
        __builtin_amdgcn_wave_barrier();

        // ---- stage 3: U = P @ upd_w2 + upd_b2 ----
        {
            v4f q = {0.f,0.f,0.f,0.f};
            #pragma unroll
            for (int mm = 0; mm < 16; ++mm) {
                const int m = 4*mm + jg4;
                const v4f wrow = *(const v4f*)(upd_w2 + m*HH + col);
                q = __builtin_elementwise_fma((v4f)(P[nn][m]), wrow, q);
            }
            #pragma unroll
            for (int c = 0; c < 4; ++c) {
                float x = q[c];
                x += __shfl_xor(x, 16, 64);
                x += __shfl_xor(x, 32, 64);
                q[c] = x;
            }
            q = q + *(const v4f*)(upd_b2 + col);
            if (jg4 == 0) *(v4f*)(&U[nn][col]) = q;
        }
        __builtin_amdgcn_wave_barrier();

        // ---- stage 4: D = relu(U @ dec_w1 + dec_b1) ----
        {
            v4f q = {0.f,0.f,0.f,0.f};
            #pragma unroll
            for (int mm = 0; mm < 16; ++mm) {
                const int m = 4*mm + jg4;
                const v4f wrow = *(const v4f*)(dec_w1 + m*HH + col);
                q = __builtin_elementwise_fma((v4f)(U[nn][m]), wrow, q);
            }
            #pragma unroll
            for (int c = 0; c < 4; ++c) {
                float x = q[c];
                x += __shfl_xor(x, 16, 64);
                x += __shfl_xor(x, 32, 64);
                q[c] = x;
            }
            q = __builtin_elementwise_max(q + *(const v4f*)(dec_b1 + col),
                                          (v4f){0.f,0.f,0.f,0.f});
            if (jg4 == 0) *(v4f*)(&D[nn][col]) = q;
        }
        __builtin_amdgcn_wave_barrier();

        // ---- final: forces = D @ dec_w2 + dec_b2 ----
        {
            const float d = D[nn][l];
            float f0 = d * dec_w2[2*l + 0];
            float f1 = d * dec_w2[2*l + 1];
            #pragma unroll
            for (int off = 32; off >= 1; off >>= 1) {
                f0 += __shfl_xor(f0, off, 64);
                f1 += __shfl_xor(f1, off, 64);
            }
            if (l == 0) {
                out[(size_t)(node0 + nn)*2 + 0] = f0 + dec_b2[0];
                out[(size_t)(node0 + nn)*2 + 1] = f1 + dec_b2[1];
            }
        }
    }
}

extern "C" void kernel_launch(void* const* d_in, const int* in_sizes, int n_in,
                              void* d_out, int out_size, void* d_ws, size_t ws_size,
                              hipStream_t stream) {
    const float* pos    = (const float*)d_in[0];
    const int*   boxp   = (const int*)  d_in[1];
    const float* enc_w1 = (const float*)d_in[2];
    const float* enc_b1 = (const float*)d_in[3];
    const float* enc_w2 = (const float*)d_in[4];
    const float* enc_b2 = (const float*)d_in[5];
    const float* msg_w1 = (const float*)d_in[6];
    const float* msg_b1 = (const float*)d_in[7];
    const float* msg_w2 = (const float*)d_in[8];
    const float* msg_b2 = (const float*)d_in[9];
    const float* upd_w1 = (const float*)d_in[10];
    const float* upd_b1 = (const float*)d_in[11];
    const float* upd_w2 = (const float*)d_in[12];
    const float* upd_b2 = (const float*)d_in[13];
    const float* dec_w1 = (const float*)d_in[14];
    const float* dec_b1 = (const float*)d_in[15];
    const float* dec_w2 = (const float*)d_in[16];
    const float* dec_b2 = (const float*)d_in[17];

    float* ws = (float*)d_ws;
    float* h  = ws;
    float* ai = ws + (size_t)NODES*HH;
    float* aj = ws + (size_t)2*NODES*HH;

    enc_kernel<<<NODES/4, 256, 0, stream>>>(pos, enc_w1, enc_b1, enc_w2, enc_b2,
                                            msg_w1, h, ai, aj);
    pairout_kernel<<<NODES/TI, 512, 0, stream>>>(pos, boxp, msg_w1, msg_b1,
                                                 ai, aj, h,
                                                 msg_w2, msg_b2,
                                                 upd_w1, upd_b1, upd_w2, upd_b2,
                                                 dec_w1, dec_b1, dec_w2, dec_b2,
                                                 (float*)d_out);
}

// Round 16
// 25.552 us; speedup vs baseline: 3.5960x; 1.0604x over previous
//
#include <hip/hip_runtime.h>

#define BB 4
#define NN 512
#define HH 64
#define NODES (BB*NN)
#define NSL 8            // j-slices == waves per fused block
#define JCH (NN/NSL)     // 64 j's per slice
#define TI 4             // i-nodes per block

typedef float v4f __attribute__((ext_vector_type(4)));

// ---------------- Kernel A: encoder MLP + message projections ----------------
// R6-proven body; block->node mapping XCD-swizzled: batch = bid&3 so batch b
// runs on XCDs {b, b+4} (default dispatch: XCD = bid % 8). aj/ai/h writes for
// a batch stay in 2 XCDs' L2s, matching pairout's readers below.
__global__ __launch_bounds__(256) void enc_kernel(
    const float* __restrict__ pos,
    const float* __restrict__ enc_w1, const float* __restrict__ enc_b1,
    const float* __restrict__ enc_w2, const float* __restrict__ enc_b2,
    const float* __restrict__ msg_w1,
    float* __restrict__ h_out, float* __restrict__ ai_out, float* __restrict__ aj_out)
{
    const int w = threadIdx.x >> 6;
    const int k = threadIdx.x & 63;
    const int bid = blockIdx.x;
    const int node = (bid & 3)*NN + (bid >> 2)*4 + w;   // batch-XCD affinity
    __shared__ float t_s[4][HH];
    __shared__ float h_s[4][HH];

    const float px = pos[node*2+0];
    const float py = pos[node*2+1];

    float t = fmaf(px, enc_w1[k], fmaf(py, enc_w1[HH + k], enc_b1[k]));
    t_s[w][k] = fmaxf(t, 0.f);
    __syncthreads();

    float h = enc_b2[k];
    #pragma unroll
    for (int m = 0; m < HH; ++m) h = fmaf(t_s[w][m], enc_w2[m*HH + k], h);
    h_s[w][k] = h;
    h_out[node*HH + k] = h;
    __syncthreads();

    float aiv = 0.f, ajv = 0.f;
    #pragma unroll
    for (int m = 0; m < HH; ++m) {
        const float hm = h_s[w][m];
        aiv = fmaf(hm, msg_w1[m*HH + k],        aiv);
        ajv = fmaf(hm, msg_w1[(HH + m)*HH + k], ajv);
    }
    ai_out[node*HH + k] = aiv;
    aj_out[node*HH + k] = ajv;
}

// ---------------- Kernel B: fused pair + output MLP (R10 verbatim body) ----------------
// Block mapping XCD-swizzled to match enc: b = bid&3 -> batch b's pair blocks
// run on XCDs {b, b+4}, reading the aj/ai/h lines the enc blocks of the SAME
// batch left in those two L2s (plus that batch's pos). Removes the ~7/8
// remote-first-touch fraction of the residual ~10us.
__global__ __launch_bounds__(512, 2) void pairout_kernel(
    const float* __restrict__ pos, const int* __restrict__ box_ptr,
    const float* __restrict__ msg_w1, const float* __restrict__ msg_b1,
    const float* __restrict__ ai, const float* __restrict__ aj,
    const float* __restrict__ h_in,
    const float* __restrict__ msg_w2, const float* __restrict__ msg_b2,
    const float* __restrict__ upd_w1, const float* __restrict__ upd_b1,
    const float* __restrict__ upd_w2, const float* __restrict__ upd_b2,
    const float* __restrict__ dec_w1, const float* __restrict__ dec_b1,
    const float* __restrict__ dec_w2, const float* __restrict__ dec_b2,
    float* __restrict__ out)
{
    const int w  = threadIdx.x >> 6;     // wave id == j-slice
    const int l  = threadIdx.x & 63;
    const int jgrp = l >> 4;
    const int kq   = l & 15;
    const int bid = blockIdx.x;          // 0..511
    const int b   = bid & 3;             // batch-XCD affinity (XCD = bid%8)
    const int i0  = ((bid >> 2) & 127) * TI;
    const int node0 = b*NN + i0;
    const int jch0  = w * JCH;

    __shared__ float dbuf[NSL][TI*64];
    __shared__ float acc_lds[NSL][TI][HH];
    __shared__ float A [TI][HH];
    __shared__ float Hs[TI][HH];
    __shared__ float G [TI][HH];
    __shared__ float P [TI][HH];
    __shared__ float U [TI][HH];
    __shared__ float D [TI][HH];

    // ================= pair phase (all 8 waves) =================
    {
        const float box  = (float)box_ptr[0];
        const float hbox = 0.5f * box;
        const float2* pos2 = (const float2*)pos;
        float* db = dbuf[w];

        // prefetch all 16 aj row-loads (R10, +1.1us measured)
        v4f ajr[16];
        {
            const float* ajbase = aj + (size_t)(b*NN + jch0 + jgrp)*HH + 4*kq;
            #pragma unroll
            for (int t = 0; t < 16; ++t)
                ajr[t] = *(const v4f*)(ajbase + (size_t)t*4*HH);
        }

        const v4f wd4 = *(const v4f*)(msg_w1 + 2*HH*HH + 4*kq);
        const v4f b1  = *(const v4f*)(msg_b1 + 4*kq);
        v4f base4[TI];
        float2 pi[TI];
        #pragma unroll
        for (int ii = 0; ii < TI; ++ii) {
            base4[ii] = *(const v4f*)(ai + (size_t)(node0 + ii)*HH + 4*kq) + b1;
            pi[ii] = pos2[node0 + ii];
        }

        // distances: lane l handles j = jch0 + l for all TI i's
        {
            const float2 pj = pos2[b*NN + jch0 + l];
            #pragma unroll
            for (int ii = 0; ii < TI; ++ii) {
                float dx = pj.x - pi[ii].x;
                float dy = pj.y - pi[ii].y;
                dx -= (dx >  hbox) ? box : 0.f;
                dx += (dx < -hbox) ? box : 0.f;
                dy -= (dy >  hbox) ? box : 0.f;
                dy += (dy < -hbox) ? box : 0.f;
                db[ii*64 + (l&3)*16 + (l>>2)] = sqrtf(fmaf(dx, dx, dy*dy));
            }
        }
        __builtin_amdgcn_wave_barrier();

        v4f acc[TI];
        #pragma unroll
        for (int ii = 0; ii < TI; ++ii) acc[ii] = (v4f){0.f,0.f,0.f,0.f};

        #pragma unroll
        for (int t4 = 0; t4 < 4; ++t4) {
            v4f d4[TI];
            #pragma unroll
            for (int ii = 0; ii < TI; ++ii)
                d4[ii] = *(const v4f*)(db + ii*64 + jgrp*16 + 4*t4);
            #pragma unroll
            for (int u = 0; u < 4; ++u) {
                const v4f a4 = ajr[t4*4 + u];
                #pragma unroll
                for (int ii = 0; ii < TI; ++ii) {
                    const float d = d4[ii][u];
                    v4f t = __builtin_elementwise_fma((v4f)(d), wd4, a4 + base4[ii]);
                    acc[ii] += __builtin_elementwise_max(t, (v4f){0.f,0.f,0.f,0.f});
                }
            }
        }

        #pragma unroll
        for (int ii = 0; ii < TI; ++ii) {
            #pragma unroll
            for (int c = 0; c < 4; ++c) {
                float v = acc[ii][c];
                v += __shfl_xor(v, 16, 64);
                v += __shfl_xor(v, 32, 64);
                acc[ii][c] = v;
            }
        }

        // self-term (exact: d_ii==0 -> in-loop term == relu(base+aj_i))
        {
            const int ii = jgrp;
            const int i  = i0 + ii;
            v4f a = acc[ii];
            if ((i >> 6) == w) {
                const v4f ajs = *(const v4f*)(aj + (size_t)(b*NN + i)*HH + 4*kq);
                a -= __builtin_elementwise_max(base4[ii] + ajs, (v4f){0.f,0.f,0.f,0.f});
            }
            *(v4f*)(&acc_lds[w][ii][4*kq]) = a;
        }
    }
    __syncthreads();

    // ================= slice-sum + h load (split across waves) =================
    if (w < 4) {
        float a = 0.f;
        #pragma unroll
        for (int s = 0; s < NSL; ++s) a += acc_lds[s][w][l];
        A[w][l] = a;
    } else {
        const int nn = w - 4;
        Hs[nn][l] = h_in[(size_t)(node0 + nn)*HH + l];
    }
    __syncthreads();

    // ================= out phase (all 8 waves) =================
    const int nn  = w & 3;       // node within block
    const int o   = w >> 2;      // output half (0/1)
    const int jg8 = l >> 3;      // m-subset {8mm+jg8}
    const int kq8 = l & 7;       // k-quad within half
    const int ocol = o*32 + 4*kq8;
    const float inv = 1.f / (float)(NN - 1);

    {
        v4f q = {0.f,0.f,0.f,0.f};
        #pragma unroll
        for (int mm = 0; mm < 8; ++mm) {
            const int m = 8*mm + jg8;
            const v4f wrow = *(const v4f*)(msg_w2 + m*HH + ocol);
            q = __builtin_elementwise_fma((v4f)(A[nn][m]), wrow, q);
        }
        #pragma unroll
        for (int c = 0; c < 4; ++c) {
            float x = q[c];
            x += __shfl_xor(x, 8, 64);
            x += __shfl_xor(x, 16, 64);
            x += __shfl_xor(x, 32, 64);
            q[c] = x;
        }
        q = __builtin_elementwise_fma(q, (v4f)(inv), *(const v4f*)(msg_b2 + ocol));
        if (jg8 == 0) *(v4f*)(&G[nn][ocol]) = q;
    }
    __syncthreads();

    {
        v4f q = {0.f,0.f,0.f,0.f};
        #pragma unroll
        for (int mm = 0; mm < 8; ++mm) {
            const int m = 8*mm + jg8;
            const v4f wrow = *(const v4f*)(upd_w1 + m*HH + ocol);
            q = __builtin_elementwise_fma((v4f)(Hs[nn][m]), wrow, q);
        }
        #pragma unroll
        for (int mm = 0; mm < 8; ++mm) {
            const int m = 8*mm + jg8;
            const v4f wrow = *(const v4f*)(upd_w1 + (size_t)(HH + m)*HH + ocol);
            q = __builtin_elementwise_fma((v4f)(G[nn][m]), wrow, q);
        }
        #pragma unroll
        for (int c = 0; c < 4; ++c) {
            float x = q[c];
            x += __shfl_xor(x, 8, 64);
            x += __shfl_xor(x, 16, 64);
            x += __shfl_xor(x, 32, 64);
            q[c] = x;
        }
        q = __builtin_elementwise_max(q + *(const v4f*)(upd_b1 + ocol),
                                      (v4f){0.f,0.f,0.f,0.f});
        if (jg8 == 0) *(v4f*)(&P[nn][ocol]) = q;
    }
    __syncthreads();

    {
        v4f q = {0.f,0.f,0.f,0.f};
        #pragma unroll
        for (int mm = 0; mm < 8; ++mm) {
            const int m = 8*mm + jg8;
            const v4f wrow = *(const v4f*)(upd_w2 + m*HH + ocol);
            q = __builtin_elementwise_fma((v4f)(P[nn][m]), wrow, q);
        }
        #pragma unroll
        for (int c = 0; c < 4; ++c) {
            float x = q[c];
            x += __shfl_xor(x, 8, 64);
            x += __shfl_xor(x, 16, 64);
            x += __shfl_xor(x, 32, 64);
            q[c] = x;
        }
        q = q + *(const v4f*)(upd_b2 + ocol);
        if (jg8 == 0) *(v4f*)(&U[nn][ocol]) = q;
    }
    __syncthreads();

    {
        v4f q = {0.f,0.f,0.f,0.f};
        #pragma unroll
        for (int mm = 0; mm < 8; ++mm) {
            const int m = 8*mm + jg8;
            const v4f wrow = *(const v4f*)(dec_w1 + m*HH + ocol);
            q = __builtin_elementwise_fma((v4f)(U[nn][m]), wrow, q);
        }
        #pragma unroll
        for (int c = 0; c < 4; ++c) {
            float x = q[c];
            x += __shfl_xor(x, 8, 64);
            x += __shfl_xor(x, 16, 64);
            x += __shfl_xor(x, 32, 64);
            q[c] = x;
        }
        q = __builtin_elementwise_max(q + *(const v4f*)(dec_b1 + ocol),
                                      (v4f){0.f,0.f,0.f,0.f});
        if (jg8 == 0) *(v4f*)(&D[nn][ocol]) = q;
    }
    __syncthreads();

    if (w < 4) {
        const float d = D[w][l];
        float f0 = d * dec_w2[2*l + 0];
        float f1 = d * dec_w2[2*l + 1];
        #pragma unroll
        for (int off = 32; off >= 1; off >>= 1) {
            f0 += __shfl_xor(f0, off, 64);
            f1 += __shfl_xor(f1, off, 64);
        }
        if (l == 0) {
            out[(size_t)(node0 + w)*2 + 0] = f0 + dec_b2[0];
            out[(size_t)(node0 + w)*2 + 1] = f1 + dec_b2[1];
        }
    }
}

extern "C" void kernel_launch(void* const* d_in, const int* in_sizes, int n_in,
                              void* d_out, int out_size, void* d_ws, size_t ws_size,
                              hipStream_t stream) {
    const float* pos    = (const float*)d_in[0];
    const int*   boxp   = (const int*)  d_in[1];
    const float* enc_w1 = (const float*)d_in[2];
    const float* enc_b1 = (const float*)d_in[3];
    const float* enc_w2 = (const float*)d_in[4];
    const float* enc_b2 = (const float*)d_in[5];
    const float* msg_w1 = (const float*)d_in[6];
    const float* msg_b1 = (const float*)d_in[7];
    const float* msg_w2 = (const float*)d_in[8];
    const float* msg_b2 = (const float*)d_in[9];
    const float* upd_w1 = (const float*)d_in[10];
    const float* upd_b1 = (const float*)d_in[11];
    const float* upd_w2 = (const float*)d_in[12];
    const float* upd_b2 = (const float*)d_in[13];
    const float* dec_w1 = (const float*)d_in[14];
    const float* dec_b1 = (const float*)d_in[15];
    const float* dec_w2 = (const float*)d_in[16];
    const float* dec_b2 = (const float*)d_in[17];

    float* ws = (float*)d_ws;
    float* h  = ws;
    float* ai = ws + (size_t)NODES*HH;
    float* aj = ws + (size_t)2*NODES*HH;

    enc_kernel<<<NODES/4, 256, 0, stream>>>(pos, enc_w1, enc_b1, enc_w2, enc_b2,
                                            msg_w1, h, ai, aj);
    pairout_kernel<<<NODES/TI, 512, 0, stream>>>(pos, boxp, msg_w1, msg_b1,
                                                 ai, aj, h,
                                                 msg_w2, msg_b2,
                                                 upd_w1, upd_b1, upd_w2, upd_b2,
                                                 dec_w1, dec_b1, dec_w2, dec_b2,
                                                 (float*)d_out);
}